// Round 1
// baseline (590.301 us; speedup 1.0000x reference)
//
#include <hip/hip_runtime.h>
#include <stdint.h>

#define HW 16384
#define CDIM 768
#define EPSF 1e-8f

typedef float f32x4  __attribute__((ext_vector_type(4)));
typedef float f32x16 __attribute__((ext_vector_type(16)));
typedef int   i32x8  __attribute__((ext_vector_type(8)));
typedef uint32_t u32x4 __attribute__((ext_vector_type(4)));

__device__ inline void async16(const void* g, void* l) {
    __builtin_amdgcn_global_load_lds(
        (const __attribute__((address_space(1))) uint32_t*)g,
        (__attribute__((address_space(3))) uint32_t*)l, 16, 0, 0);
}

__device__ inline uint32_t pk4_fp8(float v0, float v1, float v2, float v3) {
    uint32_t r = __builtin_amdgcn_cvt_pk_fp8_f32(v0, v1, 0, false);
    r = __builtin_amdgcn_cvt_pk_fp8_f32(v2, v3, r, true);
    return r;   // bytes [v0,v1,v2,v3] little-endian
}

// ---- Kernel 1: fused transpose [C][HW] fp32 -> [HW][C] fp8 + column sum-sq ----
// z=0: a (scale x16), z=1: b (scale x8, RAW; normalization in GEMM epilogue).
__global__ void __launch_bounds__(256)
transpose_fp8_norm(const float* __restrict__ a, const float* __restrict__ b,
                   uint8_t* __restrict__ at8, uint8_t* __restrict__ bn8,
                   float* __restrict__ sumsq_a, float* __restrict__ sumsq_b) {
    const int z = blockIdx.z;
    const float* src = z ? b : a;
    uint8_t* dst = z ? bn8 : at8;
    float* sums = z ? sumsq_b : sumsq_a;
    const float mult = z ? 8.0f : 16.0f;

    __shared__ float tile[64][65];   // [channel][spatial], +1 pad
    const int s0 = blockIdx.x * 64, c0 = blockIdx.y * 64;
    const int tx = threadIdx.x & 63, ty = threadIdx.x >> 6;
#pragma unroll
    for (int p = 0; p < 16; ++p) {
        int cl = p * 4 + ty;
        tile[cl][tx] = src[(size_t)(c0 + cl) * HW + s0 + tx];
    }
    __syncthreads();

    const int chgrp = tx & 15, rowsub = tx >> 4;
    uint32_t* dst32 = (uint32_t*)dst;
#pragma unroll
    for (int p = 0; p < 4; ++p) {
        int sl = p * 16 + ty * 4 + rowsub;
        float v0 = tile[chgrp * 4 + 0][sl];
        float v1 = tile[chgrp * 4 + 1][sl];
        float v2 = tile[chgrp * 4 + 2][sl];
        float v3 = tile[chgrp * 4 + 3][sl];
        float part = v0 * v0 + v1 * v1 + v2 * v2 + v3 * v3;  // raw sum-sq
        dst32[(size_t)(s0 + sl) * (CDIM / 4) + (c0 >> 2) + chgrp] =
            pk4_fp8(v0 * mult, v1 * mult, v2 * mult, v3 * mult);
#pragma unroll
        for (int m = 1; m < 16; m <<= 1) part += __shfl_xor(part, m, 64);
        if (chgrp == 0) atomicAdd(&sums[s0 + sl], part);
    }
}

// ---- Kernel 2: MX-scaled fp8 GEMM + normalize + argmax epilogue ----
// Round 9 restructure: 32x32x64 MFMA (same MX rate as 16x16x128) with
// register-cached fragments. Old loop re-read A from LDS 4x -> 40
// ds_read_b128/wave/K-step -> 16.1 GB LDS reads -> LDS-issue-bound at
// ~12cy/b128 (MfmaUtil 21%). New loop reads every A/B byte exactly once:
// ks{0,1} -> {af0,af1 held, bg transient} -> 16 b128/wave/K-step (2.5x cut).
// Live 8-wide tuples: 3 max (spill threshold from round 7/8 was 5).
// Frag rows are lane&31 and (wi*64+m*32)&7==0, so the chunk-XOR swizzle
// key stays lane&7 -- identical conflict-free structure to round 8.
// C/D layout (32x32, shape-determined): col=lane&31,
// row=(reg&3)+8*(reg>>2)+4*(lane>>5).
__global__ void
gemm_argmax(const uint8_t* __restrict__ at8, const uint8_t* __restrict__ bn8,
            const float* __restrict__ sumsq_b,
            unsigned long long* __restrict__ best) {
    __shared__ uint8_t Al[128 * 128];
    __shared__ uint8_t Bl[128 * 128];

    const int g = blockIdx.x;          // 0..16383
    const int xcd    = g & 7;
    const int s      = g >> 3;
    const int super  = s >> 5;         // 32 blocks / supertile
    const int within = s & 31;
    const int si = super >> 4;         // 4 i-tiles per supertile row
    const int sj = super & 15;         // 8 j-tiles per supertile col
    const int it = xcd * 16 + si * 4 + (within & 3);
    const int jt = sj * 8 + (within >> 2);

    const int i0 = it * 128, j0 = jt * 128;
    const int tid = threadIdx.x;
    const int lane = tid & 63, w = tid >> 6;
    const int wi = w & 1, wj = w >> 1;
    const int l31 = lane & 31, hi = lane >> 5;

    f32x16 acc[2][2] = {};

    // staging: per issue e (8 rows), lane l -> row e*8+(l>>3),
    // global chunk (l&7)^(l>>3), LDS slot lane*16 (contiguous)
    const int srow = lane >> 3;
    const int schunk = ((lane & 7) ^ srow) * 16;
    const uint8_t* gA = at8 + (size_t)(i0 + w * 32 + srow) * CDIM + schunk;
    const uint8_t* gB = bn8 + (size_t)(j0 + w * 32 + srow) * CDIM + schunk;
    uint8_t* lA = &Al[w * 32 * 128];
    uint8_t* lB = &Bl[w * 32 * 128];

    // fragment read bases: row = (wi|wj)*64 + m*32 + l31, k-half hi
    const int rA0 = (wi * 64 + l31) * 128;
    const int rB0 = (wj * 64 + l31) * 128;
    // phys chunk of logical chunk (ks*4 + hi*2): XOR with row&7 == lane&7
    const int cks0 = (((0) + hi * 2) ^ (lane & 7)) * 16;
    const int cks1 = (((4) + hi * 2) ^ (lane & 7)) * 16;

#pragma unroll 1
    for (int kk = 0; kk < CDIM; kk += 128) {
#pragma unroll
        for (int e = 0; e < 4; ++e) {
            async16(gA + kk + e * 8 * CDIM, lA + e * 1024);
            async16(gB + kk + e * 8 * CDIM, lB + e * 1024);
        }
        __syncthreads();

#pragma unroll
        for (int ks = 0; ks < 2; ++ks) {
            const int c0 = ks ? cks1 : cks0;
            i32x8 af0, af1, bg;
            *(u32x4*)&af0       = *(const u32x4*)&Al[rA0 + c0];
            *((u32x4*)&af0 + 1) = *(const u32x4*)&Al[rA0 + (c0 ^ 16)];
            *(u32x4*)&af1       = *(const u32x4*)&Al[rA0 + 4096 + c0];
            *((u32x4*)&af1 + 1) = *(const u32x4*)&Al[rA0 + 4096 + (c0 ^ 16)];

            *(u32x4*)&bg        = *(const u32x4*)&Bl[rB0 + c0];
            *((u32x4*)&bg + 1)  = *(const u32x4*)&Bl[rB0 + (c0 ^ 16)];
            acc[0][0] = __builtin_amdgcn_mfma_scale_f32_32x32x64_f8f6f4(
                af0, bg, acc[0][0], 0, 0, 0, 0x7F7F7F7F, 0, 0x7F7F7F7F);
            acc[1][0] = __builtin_amdgcn_mfma_scale_f32_32x32x64_f8f6f4(
                af1, bg, acc[1][0], 0, 0, 0, 0x7F7F7F7F, 0, 0x7F7F7F7F);

            *(u32x4*)&bg        = *(const u32x4*)&Bl[rB0 + 4096 + c0];
            *((u32x4*)&bg + 1)  = *(const u32x4*)&Bl[rB0 + 4096 + (c0 ^ 16)];
            acc[0][1] = __builtin_amdgcn_mfma_scale_f32_32x32x64_f8f6f4(
                af0, bg, acc[0][1], 0, 0, 0, 0x7F7F7F7F, 0, 0x7F7F7F7F);
            acc[1][1] = __builtin_amdgcn_mfma_scale_f32_32x32x64_f8f6f4(
                af1, bg, acc[1][1], 0, 0, 0, 0x7F7F7F7F, 0, 0x7F7F7F7F);
        }
        __syncthreads();
    }

    // epilogue: normalize by per-j denom, then argmax over this block's j's
    float invd[2];
#pragma unroll
    for (int n = 0; n < 2; ++n) {
        float sq = sumsq_b[j0 + wj * 64 + n * 32 + l31];
        invd[n] = 1.0f / (sqrtf(sq + EPSF) + EPSF);
    }
#pragma unroll
    for (int m = 0; m < 2; ++m) {
#pragma unroll
        for (int r = 0; r < 16; ++r) {
            float v = acc[m][0][r] * invd[0];
            int j = j0 + wj * 64 + l31;
            float vn = acc[m][1][r] * invd[1];
            if (vn > v) { v = vn; j = j0 + wj * 64 + 32 + l31; }  // strict >
#pragma unroll
            for (int msk = 1; msk < 32; msk <<= 1) {
                float ov = __shfl_xor(v, msk, 64);
                int   oj = __shfl_xor(j, msk, 64);
                if (ov > v || (ov == v && oj < j)) { v = ov; j = oj; }
            }
            if (l31 == 0) {
                int gi = i0 + wi * 64 + m * 32 + (r & 3) + 8 * (r >> 2) + 4 * hi;
                uint32_t u = __float_as_uint(v);
                u = (u & 0x80000000u) ? ~u : (u | 0x80000000u);  // orderable f32
                unsigned long long packed =
                    ((unsigned long long)u << 32) | (uint32_t)(~(uint32_t)j);
                atomicMax(&best[gi], packed);  // ties -> larger ~j -> smaller j
            }
        }
    }
}

// ---- Kernel 3: final loss from stored argmax dot (no gather) ----
// stored v = 128 * dot(a_i, b_j) / denom_b[j]  (fp8 dot, fp32 denom)
__global__ void loss_reduce(const unsigned long long* __restrict__ best,
                            const float* __restrict__ sumsq_a,
                            const float* __restrict__ sumsq_b,
                            float* __restrict__ out) {
    int i = blockIdx.x * 256 + threadIdx.x;
    unsigned long long pk = best[i];
    uint32_t x = (uint32_t)(pk >> 32);
    float v = (x & 0x80000000u) ? __uint_as_float(x & 0x7fffffffu)
                                : __uint_as_float(~x);
    int j = (int)(~(uint32_t)pk);
    float sb = sumsq_b[j];
    float denb = sqrtf(sb + EPSF) + EPSF;
    float dot = v * denb * (1.0f / 128.0f);
    float cs = dot / ((sqrtf(sumsq_a[i]) + EPSF) * (sqrtf(sb) + EPSF));
    float term = 1.0f - cs;
#pragma unroll
    for (int m = 32; m; m >>= 1) term += __shfl_down(term, m, 64);
    __shared__ float red[4];
    int wv = threadIdx.x >> 6, lane = threadIdx.x & 63;
    if (lane == 0) red[wv] = term;
    __syncthreads();
    if (threadIdx.x == 0) {
        float ssum = (red[0] + red[1] + red[2] + red[3]) * (1.0f / HW);
        atomicAdd(out, ssum);
    }
}

extern "C" void kernel_launch(void* const* d_in, const int* in_sizes, int n_in,
                              void* d_out, int out_size, void* d_ws, size_t ws_size,
                              hipStream_t stream) {
    const float* a = (const float*)d_in[0];
    const float* b = (const float*)d_in[1];
    char* ws = (char*)d_ws;

    const size_t T_BYTES = (size_t)HW * CDIM;   // 12.58 MB per fp8 matrix
    uint8_t* at8 = (uint8_t*)ws;
    uint8_t* bn8 = (uint8_t*)(ws + T_BYTES);
    float* sumsq_a = (float*)(ws + 2 * T_BYTES);
    float* sumsq_b = (float*)(ws + 2 * T_BYTES + HW * sizeof(float));
    unsigned long long* best =
        (unsigned long long*)(ws + 2 * T_BYTES + 2 * HW * sizeof(float));

    // zero sumsq_a + sumsq_b + best in one contiguous memset
    hipMemsetAsync(sumsq_a, 0, 2 * HW * sizeof(float) + HW * sizeof(unsigned long long),
                   stream);
    hipMemsetAsync(d_out, 0, out_size * sizeof(float), stream);

    dim3 tg(HW / 64, CDIM / 64, 2);
    transpose_fp8_norm<<<tg, 256, 0, stream>>>(a, b, at8, bn8, sumsq_a, sumsq_b);
    gemm_argmax<<<(HW / 128) * (HW / 128), 256, 0, stream>>>(at8, bn8, sumsq_b, best);
    loss_reduce<<<HW / 256, 256, 0, stream>>>(best, sumsq_a, sumsq_b, (float*)d_out);
}

// Round 2
// 418.543 us; speedup vs baseline: 1.4104x; 1.4104x over previous
//
#include <hip/hip_runtime.h>
#include <stdint.h>

#define HW 16384
#define CDIM 768
#define EPSF 1e-8f

typedef float f32x4  __attribute__((ext_vector_type(4)));
typedef float f32x16 __attribute__((ext_vector_type(16)));
typedef int   i32x8  __attribute__((ext_vector_type(8)));
typedef uint32_t u32x4 __attribute__((ext_vector_type(4)));

__device__ inline void async16(const void* g, void* l) {
    __builtin_amdgcn_global_load_lds(
        (const __attribute__((address_space(1))) uint32_t*)g,
        (__attribute__((address_space(3))) uint32_t*)l, 16, 0, 0);
}

__device__ inline uint32_t pk4_fp8(float v0, float v1, float v2, float v3) {
    uint32_t r = __builtin_amdgcn_cvt_pk_fp8_f32(v0, v1, 0, false);
    r = __builtin_amdgcn_cvt_pk_fp8_f32(v2, v3, r, true);
    return r;   // bytes [v0,v1,v2,v3] little-endian
}

// ---- Kernel 1: fused transpose [C][HW] fp32 -> [HW][C] fp8 + column sum-sq ----
// z=0: a (scale x16), z=1: b (scale x8, RAW; normalization in GEMM epilogue).
__global__ void __launch_bounds__(256)
transpose_fp8_norm(const float* __restrict__ a, const float* __restrict__ b,
                   uint8_t* __restrict__ at8, uint8_t* __restrict__ bn8,
                   float* __restrict__ sumsq_a, float* __restrict__ sumsq_b) {
    const int z = blockIdx.z;
    const float* src = z ? b : a;
    uint8_t* dst = z ? bn8 : at8;
    float* sums = z ? sumsq_b : sumsq_a;
    const float mult = z ? 8.0f : 16.0f;

    __shared__ float tile[64][65];   // [channel][spatial], +1 pad
    const int s0 = blockIdx.x * 64, c0 = blockIdx.y * 64;
    const int tx = threadIdx.x & 63, ty = threadIdx.x >> 6;
#pragma unroll
    for (int p = 0; p < 16; ++p) {
        int cl = p * 4 + ty;
        tile[cl][tx] = src[(size_t)(c0 + cl) * HW + s0 + tx];
    }
    __syncthreads();

    const int chgrp = tx & 15, rowsub = tx >> 4;
    uint32_t* dst32 = (uint32_t*)dst;
#pragma unroll
    for (int p = 0; p < 4; ++p) {
        int sl = p * 16 + ty * 4 + rowsub;
        float v0 = tile[chgrp * 4 + 0][sl];
        float v1 = tile[chgrp * 4 + 1][sl];
        float v2 = tile[chgrp * 4 + 2][sl];
        float v3 = tile[chgrp * 4 + 3][sl];
        float part = v0 * v0 + v1 * v1 + v2 * v2 + v3 * v3;  // raw sum-sq
        dst32[(size_t)(s0 + sl) * (CDIM / 4) + (c0 >> 2) + chgrp] =
            pk4_fp8(v0 * mult, v1 * mult, v2 * mult, v3 * mult);
#pragma unroll
        for (int m = 1; m < 16; m <<= 1) part += __shfl_xor(part, m, 64);
        if (chgrp == 0) atomicAdd(&sums[s0 + sl], part);
    }
}

// ---- Kernel 2: MX-scaled fp8 GEMM + normalize + argmax epilogue ----
// Round 10: SWAPPED operands (T12 trick). mfma(bg, af) transposes C:
// rows (reg-indexed) = j, cols (lane-indexed) = i. Argmax over j is now a
// LANE-LOCAL register compare chain + one shfl_xor(32) per mi -- 4 DS
// instr/wave vs round-9's 320 (the 320 shuffles were ~205us of LDS-pipe
// time; SQ_LDS_BANK_CONFLICT identical across rounds 0/1 proved conflicts
// are write-side-fixed, and the epilogue shuffle delta matched the
// round-0->1 regression). Normalization denom is now reg-indexed: each
// lane loads its 16 sumsq_b[j] per nj from L1 (2 addrs/wave per r ->
// broadcast). Main loop unchanged from round 9: every A/B byte read from
// LDS exactly once (16 b128/wave/K-step), 3 live 8-wide tuples max.
// C/D layout (32x32, shape-determined): col=lane&31,
// row=(reg&3)+8*(reg>>2)+4*(lane>>5).
__global__ void
gemm_argmax(const uint8_t* __restrict__ at8, const uint8_t* __restrict__ bn8,
            const float* __restrict__ sumsq_b,
            unsigned long long* __restrict__ best) {
    __shared__ uint8_t Al[128 * 128];
    __shared__ uint8_t Bl[128 * 128];

    const int g = blockIdx.x;          // 0..16383
    const int xcd    = g & 7;
    const int s      = g >> 3;
    const int super  = s >> 5;         // 32 blocks / supertile
    const int within = s & 31;
    const int si = super >> 4;         // 4 i-tiles per supertile row
    const int sj = super & 15;         // 8 j-tiles per supertile col
    const int it = xcd * 16 + si * 4 + (within & 3);
    const int jt = sj * 8 + (within >> 2);

    const int i0 = it * 128, j0 = jt * 128;
    const int tid = threadIdx.x;
    const int lane = tid & 63, w = tid >> 6;
    const int wi = w & 1, wj = w >> 1;
    const int l31 = lane & 31, hi = lane >> 5;

    f32x16 acc[2][2] = {};   // [nj][mi]: rows j, cols i (swapped operands)

    // staging: per issue e (8 rows), lane l -> row e*8+(l>>3),
    // global chunk (l&7)^(l>>3), LDS slot lane*16 (contiguous)
    const int srow = lane >> 3;
    const int schunk = ((lane & 7) ^ srow) * 16;
    const uint8_t* gA = at8 + (size_t)(i0 + w * 32 + srow) * CDIM + schunk;
    const uint8_t* gB = bn8 + (size_t)(j0 + w * 32 + srow) * CDIM + schunk;
    uint8_t* lA = &Al[w * 32 * 128];
    uint8_t* lB = &Bl[w * 32 * 128];

    // fragment read bases: row = (wi|wj)*64 + m*32 + l31, k-half hi
    const int rA0 = (wi * 64 + l31) * 128;
    const int rB0 = (wj * 64 + l31) * 128;
    // phys chunk of logical chunk (ks*4 + hi*2): XOR with row&7 == lane&7
    const int cks0 = (((0) + hi * 2) ^ (lane & 7)) * 16;
    const int cks1 = (((4) + hi * 2) ^ (lane & 7)) * 16;

#pragma unroll 1
    for (int kk = 0; kk < CDIM; kk += 128) {
#pragma unroll
        for (int e = 0; e < 4; ++e) {
            async16(gA + kk + e * 8 * CDIM, lA + e * 1024);
            async16(gB + kk + e * 8 * CDIM, lB + e * 1024);
        }
        __syncthreads();

#pragma unroll
        for (int ks = 0; ks < 2; ++ks) {
            const int c0 = ks ? cks1 : cks0;
            i32x8 af0, af1, bg;
            *(u32x4*)&af0       = *(const u32x4*)&Al[rA0 + c0];
            *((u32x4*)&af0 + 1) = *(const u32x4*)&Al[rA0 + (c0 ^ 16)];
            *(u32x4*)&af1       = *(const u32x4*)&Al[rA0 + 4096 + c0];
            *((u32x4*)&af1 + 1) = *(const u32x4*)&Al[rA0 + 4096 + (c0 ^ 16)];

            *(u32x4*)&bg        = *(const u32x4*)&Bl[rB0 + c0];
            *((u32x4*)&bg + 1)  = *(const u32x4*)&Bl[rB0 + (c0 ^ 16)];
            // A-slot = bg (j rows), B-slot = af (i cols)
            acc[0][0] = __builtin_amdgcn_mfma_scale_f32_32x32x64_f8f6f4(
                bg, af0, acc[0][0], 0, 0, 0, 0x7F7F7F7F, 0, 0x7F7F7F7F);
            acc[0][1] = __builtin_amdgcn_mfma_scale_f32_32x32x64_f8f6f4(
                bg, af1, acc[0][1], 0, 0, 0, 0x7F7F7F7F, 0, 0x7F7F7F7F);

            *(u32x4*)&bg        = *(const u32x4*)&Bl[rB0 + 4096 + c0];
            *((u32x4*)&bg + 1)  = *(const u32x4*)&Bl[rB0 + 4096 + (c0 ^ 16)];
            acc[1][0] = __builtin_amdgcn_mfma_scale_f32_32x32x64_f8f6f4(
                bg, af0, acc[1][0], 0, 0, 0, 0x7F7F7F7F, 0, 0x7F7F7F7F);
            acc[1][1] = __builtin_amdgcn_mfma_scale_f32_32x32x64_f8f6f4(
                bg, af1, acc[1][1], 0, 0, 0, 0x7F7F7F7F, 0, 0x7F7F7F7F);
        }
        __syncthreads();
    }

    // epilogue: normalize by per-j denom (reg-indexed), lane-local argmax
    // over the 32 j's this lane holds, then one hi-exchange + atomicMax.
    float bv[2] = {-1e30f, -1e30f};
    int   bj[2] = {0, 0};
#pragma unroll
    for (int nj = 0; nj < 2; ++nj) {
        float invd[16];
#pragma unroll
        for (int r = 0; r < 16; ++r) {
            int j = j0 + wj * 64 + nj * 32 + (r & 3) + 8 * (r >> 2) + 4 * hi;
            invd[r] = 1.0f / (sqrtf(sumsq_b[j] + EPSF) + EPSF);
        }
#pragma unroll
        for (int mi = 0; mi < 2; ++mi) {
#pragma unroll
            for (int r = 0; r < 16; ++r) {
                int j = j0 + wj * 64 + nj * 32 + (r & 3) + 8 * (r >> 2) + 4 * hi;
                float v = acc[nj][mi][r] * invd[r];
                if (v > bv[mi] || (v == bv[mi] && j < bj[mi])) {
                    bv[mi] = v; bj[mi] = j;
                }
            }
        }
    }
#pragma unroll
    for (int mi = 0; mi < 2; ++mi) {
        float ov = __shfl_xor(bv[mi], 32, 64);
        int   oj = __shfl_xor(bj[mi], 32, 64);
        if (ov > bv[mi] || (ov == bv[mi] && oj < bj[mi])) {
            bv[mi] = ov; bj[mi] = oj;
        }
        if (hi == 0) {
            int gi = i0 + wi * 64 + mi * 32 + l31;
            uint32_t u = __float_as_uint(bv[mi]);
            u = (u & 0x80000000u) ? ~u : (u | 0x80000000u);  // orderable f32
            unsigned long long packed =
                ((unsigned long long)u << 32) | (uint32_t)(~(uint32_t)bj[mi]);
            atomicMax(&best[gi], packed);  // ties -> larger ~j -> smaller j
        }
    }
}

// ---- Kernel 3: final loss from stored argmax dot (no gather) ----
// stored v = 128 * dot(a_i, b_j) / denom_b[j]  (fp8 dot, fp32 denom)
__global__ void loss_reduce(const unsigned long long* __restrict__ best,
                            const float* __restrict__ sumsq_a,
                            const float* __restrict__ sumsq_b,
                            float* __restrict__ out) {
    int i = blockIdx.x * 256 + threadIdx.x;
    unsigned long long pk = best[i];
    uint32_t x = (uint32_t)(pk >> 32);
    float v = (x & 0x80000000u) ? __uint_as_float(x & 0x7fffffffu)
                                : __uint_as_float(~x);
    int j = (int)(~(uint32_t)pk);
    float sb = sumsq_b[j];
    float denb = sqrtf(sb + EPSF) + EPSF;
    float dot = v * denb * (1.0f / 128.0f);
    float cs = dot / ((sqrtf(sumsq_a[i]) + EPSF) * (sqrtf(sb) + EPSF));
    float term = 1.0f - cs;
#pragma unroll
    for (int m = 32; m; m >>= 1) term += __shfl_down(term, m, 64);
    __shared__ float red[4];
    int wv = threadIdx.x >> 6, lane = threadIdx.x & 63;
    if (lane == 0) red[wv] = term;
    __syncthreads();
    if (threadIdx.x == 0) {
        float ssum = (red[0] + red[1] + red[2] + red[3]) * (1.0f / HW);
        atomicAdd(out, ssum);
    }
}

extern "C" void kernel_launch(void* const* d_in, const int* in_sizes, int n_in,
                              void* d_out, int out_size, void* d_ws, size_t ws_size,
                              hipStream_t stream) {
    const float* a = (const float*)d_in[0];
    const float* b = (const float*)d_in[1];
    char* ws = (char*)d_ws;

    const size_t T_BYTES = (size_t)HW * CDIM;   // 12.58 MB per fp8 matrix
    uint8_t* at8 = (uint8_t*)ws;
    uint8_t* bn8 = (uint8_t*)(ws + T_BYTES);
    float* sumsq_a = (float*)(ws + 2 * T_BYTES);
    float* sumsq_b = (float*)(ws + 2 * T_BYTES + HW * sizeof(float));
    unsigned long long* best =
        (unsigned long long*)(ws + 2 * T_BYTES + 2 * HW * sizeof(float));

    // zero sumsq_a + sumsq_b + best in one contiguous memset
    hipMemsetAsync(sumsq_a, 0, 2 * HW * sizeof(float) + HW * sizeof(unsigned long long),
                   stream);
    hipMemsetAsync(d_out, 0, out_size * sizeof(float), stream);

    dim3 tg(HW / 64, CDIM / 64, 2);
    transpose_fp8_norm<<<tg, 256, 0, stream>>>(a, b, at8, bn8, sumsq_a, sumsq_b);
    gemm_argmax<<<(HW / 128) * (HW / 128), 256, 0, stream>>>(at8, bn8, sumsq_b, best);
    loss_reduce<<<HW / 256, 256, 0, stream>>>(best, sumsq_a, sumsq_b, (float*)d_out);
}

// Round 3
// 375.994 us; speedup vs baseline: 1.5700x; 1.1132x over previous
//
#include <hip/hip_runtime.h>
#include <stdint.h>

#define HW 16384
#define CDIM 768
#define EPSF 1e-8f

typedef float f32x4  __attribute__((ext_vector_type(4)));
typedef float f32x16 __attribute__((ext_vector_type(16)));
typedef int   i32x8  __attribute__((ext_vector_type(8)));
typedef uint32_t u32x4 __attribute__((ext_vector_type(4)));

__device__ inline void async16(const void* g, void* l) {
    __builtin_amdgcn_global_load_lds(
        (const __attribute__((address_space(1))) uint32_t*)g,
        (__attribute__((address_space(3))) uint32_t*)l, 16, 0, 0);
}

__device__ inline uint32_t pk4_fp8(float v0, float v1, float v2, float v3) {
    uint32_t r = __builtin_amdgcn_cvt_pk_fp8_f32(v0, v1, 0, false);
    r = __builtin_amdgcn_cvt_pk_fp8_f32(v2, v3, r, true);
    return r;   // bytes [v0,v1,v2,v3] little-endian
}

// ---- Kernel 1: fused transpose [C][HW] fp32 -> [HW][C] fp8 + column sum-sq ----
// z=0: a (scale x16), z=1: b (scale x8, RAW; normalization in GEMM epilogue).
__global__ void __launch_bounds__(256)
transpose_fp8_norm(const float* __restrict__ a, const float* __restrict__ b,
                   uint8_t* __restrict__ at8, uint8_t* __restrict__ bn8,
                   float* __restrict__ sumsq_a, float* __restrict__ sumsq_b) {
    const int z = blockIdx.z;
    const float* src = z ? b : a;
    uint8_t* dst = z ? bn8 : at8;
    float* sums = z ? sumsq_b : sumsq_a;
    const float mult = z ? 8.0f : 16.0f;

    __shared__ float tile[64][65];   // [channel][spatial], +1 pad
    const int s0 = blockIdx.x * 64, c0 = blockIdx.y * 64;
    const int tx = threadIdx.x & 63, ty = threadIdx.x >> 6;
#pragma unroll
    for (int p = 0; p < 16; ++p) {
        int cl = p * 4 + ty;
        tile[cl][tx] = src[(size_t)(c0 + cl) * HW + s0 + tx];
    }
    __syncthreads();

    const int chgrp = tx & 15, rowsub = tx >> 4;
    uint32_t* dst32 = (uint32_t*)dst;
#pragma unroll
    for (int p = 0; p < 4; ++p) {
        int sl = p * 16 + ty * 4 + rowsub;
        float v0 = tile[chgrp * 4 + 0][sl];
        float v1 = tile[chgrp * 4 + 1][sl];
        float v2 = tile[chgrp * 4 + 2][sl];
        float v3 = tile[chgrp * 4 + 3][sl];
        float part = v0 * v0 + v1 * v1 + v2 * v2 + v3 * v3;  // raw sum-sq
        dst32[(size_t)(s0 + sl) * (CDIM / 4) + (c0 >> 2) + chgrp] =
            pk4_fp8(v0 * mult, v1 * mult, v2 * mult, v3 * mult);
#pragma unroll
        for (int m = 1; m < 16; m <<= 1) part += __shfl_xor(part, m, 64);
        if (chgrp == 0) atomicAdd(&sums[s0 + sl], part);
    }
}

// ---- Kernel 1b: precompute inverse denominators for b (after atomics) ----
__global__ void prep_invd(const float* __restrict__ sumsq_b,
                          float* __restrict__ invdb) {
    int j = blockIdx.x * 256 + threadIdx.x;
    invdb[j] = 1.0f / (sqrtf(sumsq_b[j] + EPSF) + EPSF);
}

// ---- Kernel 2: MX-scaled fp8 GEMM + normalize + argmax epilogue ----
// Round 11: BK=64 DOUBLE-BUFFERED pipeline (T3 2-phase recipe) in the same
// 32 KB LDS (2 x 8 KB per operand). Round-2's __syncthreads drained
// vmcnt(0) at ISSUE time (full L2/L3 latency exposed every K-step; with
// only ~3.5 blocks/CU TLP couldn't hide it). Now: STAGE(next) is issued
// BEFORE compute(cur); drain is asm vmcnt(0) AFTER compute + raw
// s_barrier (one barrier/iter; reads are lgkm-drained by MFMA consumption
// before the barrier, staged buffer was last read two iters ago).
// LDS read/MFMA totals unchanged vs round 2 (96 b128 + 48 MFMA/wave).
// Swizzle re-derived for 64B rows: phys chunk = logical ^ ((row>>1)&3),
// write-linear LDS + pre-swizzled global source + swizzled read (rule 21
// involution). Same <=8-addr-per-bank-group structure as round 2's
// measured-fine layout. Epilogue: invdb precomputed (kernel 1b) -> 8x
// float4 L1 loads replace 32 sqrt+rcp TRANS ops per wave.
// Swapped operands (round 2): rows=j (reg), cols=i (lane); argmax is
// lane-local. C/D 32x32 layout: col=lane&31, row=(reg&3)+8*(reg>>2)+4*hi.
__global__ void
gemm_argmax(const uint8_t* __restrict__ at8, const uint8_t* __restrict__ bn8,
            const float* __restrict__ invdb,
            unsigned long long* __restrict__ best) {
    __shared__ uint8_t Al[2 * 8192];   // [buf][128 rows][64 B]
    __shared__ uint8_t Bl[2 * 8192];

    const int g = blockIdx.x;          // 0..16383
    const int xcd    = g & 7;
    const int s      = g >> 3;
    const int super  = s >> 5;         // 32 blocks / supertile
    const int within = s & 31;
    const int si = super >> 4;         // 4 i-tiles per supertile row
    const int sj = super & 15;         // 8 j-tiles per supertile col
    const int it = xcd * 16 + si * 4 + (within & 3);
    const int jt = sj * 8 + (within >> 2);

    const int i0 = it * 128, j0 = jt * 128;
    const int tid = threadIdx.x;
    const int lane = tid & 63, w = tid >> 6;
    const int wi = w & 1, wj = w >> 1;
    const int l31 = lane & 31, hi = lane >> 5;

    f32x16 acc[2][2] = {};   // [nj][mi]: rows j, cols i (swapped operands)

    // staging (per 1KB issue: 16 rows x 64B): lane l -> row (l>>2),
    // global chunk (l&3)^((l>>3)&3)  [= (row>>1)&3 since issue rows are
    // multiples of 16], LDS slot lane*16 (linear).
    const int srow = lane >> 2;
    const int schunk = ((lane & 3) ^ ((lane >> 3) & 3)) * 16;
    const uint8_t* gA = at8 + (size_t)(i0 + w * 32 + srow) * CDIM + schunk;
    const uint8_t* gB = bn8 + (size_t)(j0 + w * 32 + srow) * CDIM + schunk;
    uint8_t* lA = Al + w * 2048;       // this wave's 32 rows
    uint8_t* lB = Bl + w * 2048;

    // fragment reads: row = (wi|wj)*64 (+32 for second frag) + l31;
    // lane's K-bytes = hi*32..hi*32+31 -> logical chunks hi*2, hi*2+1;
    // phys = logical ^ ((row>>1)&3)  (row>>1 mod 4 == l31>>1 mod 4).
    const int rA0 = (wi * 64 + l31) * 64;
    const int rB0 = (wj * 64 + l31) * 64;
    const int c0 = ((hi * 2) ^ ((l31 >> 1) & 3)) * 16;   // second b128 at ^16

#define STAGE(bo, kk)                                         \
    do {                                                      \
        async16(gA + (kk),             lA + (bo));            \
        async16(gA + (kk) + 16 * CDIM, lA + (bo) + 1024);     \
        async16(gB + (kk),             lB + (bo));            \
        async16(gB + (kk) + 16 * CDIM, lB + (bo) + 1024);     \
    } while (0)

#define COMPUTE(bo)                                                          \
    do {                                                                     \
        i32x8 af0, af1, bg;                                                  \
        *(u32x4*)&af0       = *(const u32x4*)&Al[(bo) + rA0 + c0];           \
        *((u32x4*)&af0 + 1) = *(const u32x4*)&Al[(bo) + rA0 + (c0 ^ 16)];    \
        *(u32x4*)&af1       = *(const u32x4*)&Al[(bo) + rA0 + 2048 + c0];    \
        *((u32x4*)&af1 + 1) = *(const u32x4*)&Al[(bo) + rA0 + 2048 + (c0 ^ 16)]; \
        *(u32x4*)&bg        = *(const u32x4*)&Bl[(bo) + rB0 + c0];           \
        *((u32x4*)&bg + 1)  = *(const u32x4*)&Bl[(bo) + rB0 + (c0 ^ 16)];    \
        acc[0][0] = __builtin_amdgcn_mfma_scale_f32_32x32x64_f8f6f4(         \
            bg, af0, acc[0][0], 0, 0, 0, 0x7F7F7F7F, 0, 0x7F7F7F7F);         \
        acc[0][1] = __builtin_amdgcn_mfma_scale_f32_32x32x64_f8f6f4(         \
            bg, af1, acc[0][1], 0, 0, 0, 0x7F7F7F7F, 0, 0x7F7F7F7F);         \
        *(u32x4*)&bg        = *(const u32x4*)&Bl[(bo) + rB0 + 2048 + c0];    \
        *((u32x4*)&bg + 1)  = *(const u32x4*)&Bl[(bo) + rB0 + 2048 + (c0 ^ 16)]; \
        acc[1][0] = __builtin_amdgcn_mfma_scale_f32_32x32x64_f8f6f4(         \
            bg, af0, acc[1][0], 0, 0, 0, 0x7F7F7F7F, 0, 0x7F7F7F7F);         \
        acc[1][1] = __builtin_amdgcn_mfma_scale_f32_32x32x64_f8f6f4(         \
            bg, af1, acc[1][1], 0, 0, 0, 0x7F7F7F7F, 0, 0x7F7F7F7F);         \
    } while (0)

    // prologue: stage tile 0, drain, barrier
    STAGE(0, 0);
    asm volatile("s_waitcnt vmcnt(0)" ::: "memory");
    __builtin_amdgcn_s_barrier();

#pragma unroll 1
    for (int t = 0; t < 11; ++t) {
        const int bo = (t & 1) * 8192;
        STAGE(bo ^ 8192, (t + 1) * 64);   // issue next tile (latency hides
        COMPUTE(bo);                      //   under this compute phase)
        asm volatile("s_waitcnt vmcnt(0)" ::: "memory");  // next tile landed
        __builtin_amdgcn_s_barrier();
    }
    COMPUTE(8192);                        // t=11, no further staging

#undef STAGE
#undef COMPUTE

    // epilogue: normalize by per-j inv-denom (precomputed, reg-indexed),
    // lane-local argmax over the 32 j's, one hi-exchange + atomicMax.
    float bv[2] = {-1e30f, -1e30f};
    int   bj[2] = {0, 0};
#pragma unroll
    for (int nj = 0; nj < 2; ++nj) {
        const int jb = j0 + wj * 64 + nj * 32 + 4 * hi;
        f32x4 iv[4];
#pragma unroll
        for (int q = 0; q < 4; ++q)
            iv[q] = *(const f32x4*)&invdb[jb + 8 * q];
#pragma unroll
        for (int mi = 0; mi < 2; ++mi) {
#pragma unroll
            for (int r = 0; r < 16; ++r) {
                int j = jb + (r & 3) + 8 * (r >> 2);
                float v = acc[nj][mi][r] * iv[r >> 2][r & 3];
                if (v > bv[mi] || (v == bv[mi] && j < bj[mi])) {
                    bv[mi] = v; bj[mi] = j;
                }
            }
        }
    }
#pragma unroll
    for (int mi = 0; mi < 2; ++mi) {
        float ov = __shfl_xor(bv[mi], 32, 64);
        int   oj = __shfl_xor(bj[mi], 32, 64);
        if (ov > bv[mi] || (ov == bv[mi] && oj < bj[mi])) {
            bv[mi] = ov; bj[mi] = oj;
        }
        if (hi == 0) {
            int gi = i0 + wi * 64 + mi * 32 + l31;
            uint32_t u = __float_as_uint(bv[mi]);
            u = (u & 0x80000000u) ? ~u : (u | 0x80000000u);  // orderable f32
            unsigned long long packed =
                ((unsigned long long)u << 32) | (uint32_t)(~(uint32_t)bj[mi]);
            atomicMax(&best[gi], packed);  // ties -> larger ~j -> smaller j
        }
    }
}

// ---- Kernel 3: final loss from stored argmax dot (no gather) ----
// stored v = 128 * dot(a_i, b_j) / denom_b[j]  (fp8 dot, fp32 denom)
__global__ void loss_reduce(const unsigned long long* __restrict__ best,
                            const float* __restrict__ sumsq_a,
                            const float* __restrict__ sumsq_b,
                            float* __restrict__ out) {
    int i = blockIdx.x * 256 + threadIdx.x;
    unsigned long long pk = best[i];
    uint32_t x = (uint32_t)(pk >> 32);
    float v = (x & 0x80000000u) ? __uint_as_float(x & 0x7fffffffu)
                                : __uint_as_float(~x);
    int j = (int)(~(uint32_t)pk);
    float sb = sumsq_b[j];
    float denb = sqrtf(sb + EPSF) + EPSF;
    float dot = v * denb * (1.0f / 128.0f);
    float cs = dot / ((sqrtf(sumsq_a[i]) + EPSF) * (sqrtf(sb) + EPSF));
    float term = 1.0f - cs;
#pragma unroll
    for (int m = 32; m; m >>= 1) term += __shfl_down(term, m, 64);
    __shared__ float red[4];
    int wv = threadIdx.x >> 6, lane = threadIdx.x & 63;
    if (lane == 0) red[wv] = term;
    __syncthreads();
    if (threadIdx.x == 0) {
        float ssum = (red[0] + red[1] + red[2] + red[3]) * (1.0f / HW);
        atomicAdd(out, ssum);
    }
}

extern "C" void kernel_launch(void* const* d_in, const int* in_sizes, int n_in,
                              void* d_out, int out_size, void* d_ws, size_t ws_size,
                              hipStream_t stream) {
    const float* a = (const float*)d_in[0];
    const float* b = (const float*)d_in[1];
    char* ws = (char*)d_ws;

    const size_t T_BYTES = (size_t)HW * CDIM;   // 12.58 MB per fp8 matrix
    uint8_t* at8 = (uint8_t*)ws;
    uint8_t* bn8 = (uint8_t*)(ws + T_BYTES);
    float* sumsq_a = (float*)(ws + 2 * T_BYTES);
    float* sumsq_b = (float*)(ws + 2 * T_BYTES + HW * sizeof(float));
    unsigned long long* best =
        (unsigned long long*)(ws + 2 * T_BYTES + 2 * HW * sizeof(float));
    float* invdb = (float*)(ws + 2 * T_BYTES + 2 * HW * sizeof(float)
                            + HW * sizeof(unsigned long long));

    // zero sumsq_a + sumsq_b + best in one contiguous memset
    hipMemsetAsync(sumsq_a, 0, 2 * HW * sizeof(float) + HW * sizeof(unsigned long long),
                   stream);
    hipMemsetAsync(d_out, 0, out_size * sizeof(float), stream);

    dim3 tg(HW / 64, CDIM / 64, 2);
    transpose_fp8_norm<<<tg, 256, 0, stream>>>(a, b, at8, bn8, sumsq_a, sumsq_b);
    prep_invd<<<HW / 256, 256, 0, stream>>>(sumsq_b, invdb);
    gemm_argmax<<<(HW / 128) * (HW / 128), 256, 0, stream>>>(at8, bn8, invdb, best);
    loss_reduce<<<HW / 256, 256, 0, stream>>>(best, sumsq_a, sumsq_b, (float*)d_out);
}